// Round 2
// baseline (8582.812 us; speedup 1.0000x reference)
//
#include <hip/hip_runtime.h>

// ---------------------------------------------------------------------------
// AdvancedStockRNN on MI355X.  B=256 T=512 DIN=64 H=256 HB=128.
// Pipeline: [f32->bf16 weight converts] -> (GEMM xg -> scan) x6 -> att GEMM ->
//           scores -> softmax-pool + BN + FC head.
// Workspace-adaptive: gate buffer XG is chunked over T (NC chunks) so the
// total footprint fits ws_size; scans checkpoint h between chunks in global.
// Scans: batch-partitioned WGs (16 rows each), recurrent weights register-
// resident as MFMA B-fragments, h in XOR-swizzled LDS double buffer, xg[t]
// double-buffered in LDS with issue-early prefetch.
// ---------------------------------------------------------------------------

typedef short sv8 __attribute__((ext_vector_type(8)));   // 8 bf16 (4 VGPR)
typedef short sv4 __attribute__((ext_vector_type(4)));
typedef float fv4 __attribute__((ext_vector_type(4)));

__device__ __forceinline__ float bf2f(short s) {
  union { unsigned u; float f; } v; v.u = ((unsigned)(unsigned short)s) << 16; return v.f;
}
__device__ __forceinline__ short f2bf(float f) {
  union { float f; unsigned u; } v; v.f = f;
  unsigned r = (v.u + 0x7fffu + ((v.u >> 16) & 1u)) >> 16;
  return (short)r;
}
__device__ __forceinline__ float sigm(float x) { return 1.f / (1.f + __expf(-x)); }
__device__ __forceinline__ float tanh_f(float x) {
  float ax = fabsf(x);
  float e = __expf(2.f * ax);              // overflow -> inf -> t = 1
  float t = 1.f - 2.f / (e + 1.f);
  return copysignf(t, x);
}

// ---------------------------------------------------------------------------
// fp32 -> bf16 convert, 4 elems/thread (n % 1024 == 0)
// ---------------------------------------------------------------------------
__global__ __launch_bounds__(256) void f2b4(const float* __restrict__ s,
                                            short* __restrict__ d, int n4) {
  int i = blockIdx.x * 256 + threadIdx.x;
  if (i < n4) {
    fv4 v = ((const fv4*)s)[i];
    sv4 o;
    o[0] = f2bf(v[0]); o[1] = f2bf(v[1]); o[2] = f2bf(v[2]); o[3] = f2bf(v[3]);
    ((sv4*)d)[i] = o;
  }
}

// ---------------------------------------------------------------------------
// GEMM: C[r, :](bf16) = act(A[arow(r), :K] @ W[N,K]^T + bias), chunk-local C.
// r = b*Tc + tl; arow = b*512 + w0 + tl.   256 thr = 4 waves, 32 rows/wave,
// A-frags in registers, W streamed (L2-resident), no LDS/barriers.
// grid.x = (256*Tc)/128.  ACT: 0 none, 1 tanh.  AF32: A is fp32.
// ---------------------------------------------------------------------------
template <int KS, int ACT, bool AF32>
__global__ __launch_bounds__(256, 4) void gemm_xw(
    const void* __restrict__ Av, const short* __restrict__ W,
    const float* __restrict__ bias, short* __restrict__ C,
    int N, int ldc, int c_off, int w0, int l2tc) {
  const int K = KS * 32;
  const int lane = threadIdx.x & 63, wv = threadIdx.x >> 6;
  const int l15 = lane & 15, q = lane >> 4;
  const int m0 = blockIdx.x * 128 + wv * 32;
  const int tcm = (1 << l2tc) - 1;

  sv8 af[2][KS];
#pragma unroll
  for (int s = 0; s < 2; ++s) {
    const int r = m0 + s * 16 + l15;
    const size_t arow = (size_t)(r >> l2tc) * 512 + w0 + (r & tcm);
    if (AF32) {
      const float* ap = (const float*)Av + arow * K + q * 8;
#pragma unroll
      for (int k = 0; k < KS; ++k) {
        fv4 lo = *(const fv4*)(ap + k * 32);
        fv4 hi = *(const fv4*)(ap + k * 32 + 4);
        sv8 o;
        o[0] = f2bf(lo[0]); o[1] = f2bf(lo[1]); o[2] = f2bf(lo[2]); o[3] = f2bf(lo[3]);
        o[4] = f2bf(hi[0]); o[5] = f2bf(hi[1]); o[6] = f2bf(hi[2]); o[7] = f2bf(hi[3]);
        af[s][k] = o;
      }
    } else {
      const short* ap = (const short*)Av + arow * K + q * 8;
#pragma unroll
      for (int k = 0; k < KS; ++k) af[s][k] = *(const sv8*)(ap + k * 32);
    }
  }
  const int N16 = N >> 4;
  for (int nt = 0; nt < N16; ++nt) {
    const short* wp = W + (size_t)(nt * 16 + l15) * K + q * 8;
    fv4 acc0 = {0.f, 0.f, 0.f, 0.f}, acc1 = {0.f, 0.f, 0.f, 0.f};
#pragma unroll
    for (int k = 0; k < KS; ++k) {
      sv8 bf = *(const sv8*)(wp + k * 32);
      acc0 = __builtin_amdgcn_mfma_f32_16x16x32_bf16(af[0][k], bf, acc0, 0, 0, 0);
      acc1 = __builtin_amdgcn_mfma_f32_16x16x32_bf16(af[1][k], bf, acc1, 0, 0, 0);
    }
    float bv = bias[nt * 16 + l15];
#pragma unroll
    for (int s = 0; s < 2; ++s) {
      fv4 a = s ? acc1 : acc0;
#pragma unroll
      for (int j = 0; j < 4; ++j) {
        float v = a[j] + bv;
        if (ACT == 1) v = tanh_f(v);
        int row = m0 + s * 16 + q * 4 + j;
        C[(size_t)row * ldc + c_off + nt * 16 + l15] = f2bf(v);
      }
    }
  }
}

// ---------------------------------------------------------------------------
// tanh-RNN scan chunk.  grid 16 x 512thr (8 waves x 32 cols).  H=256.
// xg: [B,Tc,256] bf16 chunk (includes bih), whh: [256,256] bf16, bhh f32.
// hst: [B,256] bf16 checkpoint (load unless first; always stored at end).
// ---------------------------------------------------------------------------
__global__ __launch_bounds__(512, 2) void rnn_scan(
    const short* __restrict__ xg, const short* __restrict__ whh,
    const float* __restrict__ bhh, short* __restrict__ hout,
    int w0, int Tc, int first, short* __restrict__ hst) {
  constexpr int T = 512, H = 256, NR = 16;
  __shared__ __align__(16) short hl[2][NR * H];
  __shared__ __align__(16) short xgl[2][NR * H];
  const int tid = threadIdx.x;
  const int lane = tid & 63, wv = tid >> 6;
  const int l15 = lane & 15, q = lane >> 4;
  const int r0 = blockIdx.x * NR;
  const int hc0 = wv * 32;

  sv8 wf[2][8];
  float bh[2];
#pragma unroll
  for (int s = 0; s < 2; ++s) {
    const short* wp = whh + (size_t)(hc0 + s * 16 + l15) * H + q * 8;
#pragma unroll
    for (int k = 0; k < 8; ++k) wf[s][k] = *(const sv8*)(wp + k * 32);
    bh[s] = bhh[hc0 + s * 16 + l15];
  }

  {  // init h state (swizzled layout)
    const int i = tid * 8, row = i >> 8, col = i & 255;
    const int sa = row * H + (col ^ ((row & 7) << 3));
    if (first) {
      sv8 z = {0, 0, 0, 0, 0, 0, 0, 0};
      *(sv8*)&hl[0][sa] = z;
    } else {
      *(sv8*)&hl[0][sa] = *(const sv8*)(hst + (size_t)(r0 + row) * H + col);
    }
  }
  const int f0 = tid * 8;
  const int srow = f0 >> 8, scol = f0 & 255;
  const size_t sb = ((size_t)(r0 + srow) * Tc) * H + scol;
  *(sv8*)&xgl[0][f0] = *(const sv8*)(xg + sb);
  __syncthreads();

  const int swz = (l15 & 7) << 3;
  const int qs = (q * 8) ^ (swz & 24);
  const int sh = swz & 32;

  for (int t = 0; t < Tc; ++t) {
    const int cur = t & 1, nxt = cur ^ 1;
    sv8 pf;
    if (t + 1 < Tc) pf = *(const sv8*)(xg + sb + (size_t)(t + 1) * H);

    fv4 acc[2] = {{0.f, 0.f, 0.f, 0.f}, {0.f, 0.f, 0.f, 0.f}};
    const short* hb = &hl[cur][l15 * H];
#pragma unroll
    for (int k = 0; k < 8; ++k) {
      sv8 a = *(const sv8*)(hb + (((k * 32) ^ sh) + qs));
      acc[0] = __builtin_amdgcn_mfma_f32_16x16x32_bf16(a, wf[0][k], acc[0], 0, 0, 0);
      acc[1] = __builtin_amdgcn_mfma_f32_16x16x32_bf16(a, wf[1][k], acc[1], 0, 0, 0);
    }
#pragma unroll
    for (int s = 0; s < 2; ++s) {
      const int c = hc0 + s * 16 + l15;
#pragma unroll
      for (int j = 0; j < 4; ++j) {
        const int row = q * 4 + j;
        float hv = tanh_f(bf2f(xgl[cur][row * H + c]) + acc[s][j] + bh[s]);
        short hbf = f2bf(hv);
        hl[nxt][row * H + (c ^ ((row & 7) << 3))] = hbf;
        hout[((size_t)(r0 + row) * T + w0 + t) * H + c] = hbf;
      }
    }
    if (t + 1 < Tc) *(sv8*)&xgl[nxt][f0] = pf;
    __syncthreads();
  }
  {  // store checkpoint
    const int i = tid * 8, row = i >> 8, col = i & 255;
    sv8 v = *(const sv8*)&hl[Tc & 1][row * H + (col ^ ((row & 7) << 3))];
    *(sv8*)(hst + (size_t)(r0 + row) * H + col) = v;
  }
}

// ---------------------------------------------------------------------------
// GRU scan chunk.  grid 16 x 512thr (8 waves x 32 hidden cols, gates in-lane).
// xg: [B,Tc,768] bf16 chunk (includes bih), whh: [768,256] bf16, bhh f32[768].
// ---------------------------------------------------------------------------
__global__ __launch_bounds__(512, 2) void gru_scan(
    const short* __restrict__ xg, const short* __restrict__ whh,
    const float* __restrict__ bhh, short* __restrict__ hout,
    int w0, int Tc, int first, short* __restrict__ hst) {
  constexpr int T = 512, H = 256, G = 768, NR = 16;
  __shared__ __align__(16) short hl[2][NR * H];
  __shared__ __align__(16) short xgl[2][NR * G];
  const int tid = threadIdx.x;
  const int lane = tid & 63, wv = tid >> 6;
  const int l15 = lane & 15, q = lane >> 4;
  const int r0 = blockIdx.x * NR;
  const int hc0 = wv * 32;

  sv8 wf[3][2][8];
  float bh[3][2];
#pragma unroll
  for (int g = 0; g < 3; ++g)
#pragma unroll
    for (int s = 0; s < 2; ++s) {
      const short* wp = whh + (size_t)(g * H + hc0 + s * 16 + l15) * H + q * 8;
#pragma unroll
      for (int k = 0; k < 8; ++k) wf[g][s][k] = *(const sv8*)(wp + k * 32);
      bh[g][s] = bhh[g * H + hc0 + s * 16 + l15];
    }

  {  // init h state (swizzled)
    const int i = tid * 8, row = i >> 8, col = i & 255;
    const int sa = row * H + (col ^ ((row & 7) << 3));
    if (first) {
      sv8 z = {0, 0, 0, 0, 0, 0, 0, 0};
      *(sv8*)&hl[0][sa] = z;
    } else {
      *(sv8*)&hl[0][sa] = *(const sv8*)(hst + (size_t)(r0 + row) * H + col);
    }
  }
  size_t sb[3];
  int sl[3];
#pragma unroll
  for (int c = 0; c < 3; ++c) {
    int f = c * 4096 + tid * 8, row = f / G, col = f % G;
    sb[c] = ((size_t)(r0 + row) * Tc) * G + col;
    sl[c] = f;
  }
#pragma unroll
  for (int c = 0; c < 3; ++c) *(sv8*)&xgl[0][sl[c]] = *(const sv8*)(xg + sb[c]);
  __syncthreads();

  const int swz = (l15 & 7) << 3;
  const int qs = (q * 8) ^ (swz & 24);
  const int sh = swz & 32;

  for (int t = 0; t < Tc; ++t) {
    const int cur = t & 1, nxt = cur ^ 1;
    sv8 pf0, pf1, pf2;
    if (t + 1 < Tc) {
      pf0 = *(const sv8*)(xg + sb[0] + (size_t)(t + 1) * G);
      pf1 = *(const sv8*)(xg + sb[1] + (size_t)(t + 1) * G);
      pf2 = *(const sv8*)(xg + sb[2] + (size_t)(t + 1) * G);
    }
    fv4 acc[3][2];
#pragma unroll
    for (int g = 0; g < 3; ++g)
#pragma unroll
      for (int s = 0; s < 2; ++s) acc[g][s] = (fv4){0.f, 0.f, 0.f, 0.f};

    const short* hb = &hl[cur][l15 * H];
#pragma unroll
    for (int k = 0; k < 8; ++k) {
      sv8 a = *(const sv8*)(hb + (((k * 32) ^ sh) + qs));
#pragma unroll
      for (int g = 0; g < 3; ++g)
#pragma unroll
        for (int s = 0; s < 2; ++s)
          acc[g][s] = __builtin_amdgcn_mfma_f32_16x16x32_bf16(a, wf[g][s][k], acc[g][s], 0, 0, 0);
    }
#pragma unroll
    for (int s = 0; s < 2; ++s) {
      const int c = hc0 + s * 16 + l15;
#pragma unroll
      for (int j = 0; j < 4; ++j) {
        const int row = q * 4 + j;
        const short* xr = &xgl[cur][row * G + c];
        float rr = sigm(bf2f(xr[0]) + acc[0][s][j] + bh[0][s]);
        float zz = sigm(bf2f(xr[H]) + acc[1][s][j] + bh[1][s]);
        float nn = tanh_f(bf2f(xr[2 * H]) + rr * (acc[2][s][j] + bh[2][s]));
        const int hidx = row * H + (c ^ ((row & 7) << 3));
        float hp = bf2f(hl[cur][hidx]);
        float hv = (1.f - zz) * nn + zz * hp;
        short hbf = f2bf(hv);
        hl[nxt][hidx] = hbf;
        hout[((size_t)(r0 + row) * T + w0 + t) * H + c] = hbf;
      }
    }
    if (t + 1 < Tc) {
      *(sv8*)&xgl[nxt][sl[0]] = pf0;
      *(sv8*)&xgl[nxt][sl[1]] = pf1;
      *(sv8*)&xgl[nxt][sl[2]] = pf2;
    }
    __syncthreads();
  }
  {  // store checkpoint
    const int i = tid * 8, row = i >> 8, col = i & 255;
    sv8 v = *(const sv8*)&hl[Tc & 1][row * H + (col ^ ((row & 7) << 3))];
    *(sv8*)(hst + (size_t)(r0 + row) * H + col) = v;
  }
}

// ---------------------------------------------------------------------------
// bi-GRU scan chunk (one direction per WG).  grid 32 x 512thr.
// wg<16: fwd rows, window w0f (ascending t); wg>=16: bwd, window w0b (desc).
// xgf/xgb: [B,Tc,384] bf16 chunks.  hout: [B,T,256] (fwd cols 0..127, bwd
// 128..255).  hstf/hstb: [B,128] bf16 checkpoints.
// ---------------------------------------------------------------------------
__global__ __launch_bounds__(512, 2) void bigru_scan(
    const short* __restrict__ xgf, const short* __restrict__ xgb,
    const short* __restrict__ whh_f, const short* __restrict__ whh_b,
    const float* __restrict__ bhh_f, const float* __restrict__ bhh_b,
    short* __restrict__ hout, int w0f, int w0b, int Tc, int first,
    short* __restrict__ hstf, short* __restrict__ hstb) {
  constexpr int T = 512, HB = 128, GL = 384, NR = 16, HO = 256;
  __shared__ __align__(16) short hl[2][NR * HB];
  __shared__ __align__(16) short xgl[2][NR * GL];
  const int tid = threadIdx.x;
  const int lane = tid & 63, wv = tid >> 6;
  const int l15 = lane & 15, q = lane >> 4;
  const int dir = blockIdx.x >> 4;
  const int r0 = (blockIdx.x & 15) * NR;
  const int hc0 = wv * 16;
  const short* whh = dir ? whh_b : whh_f;
  const float* bhh = dir ? bhh_b : bhh_f;
  const short* xg = dir ? xgb : xgf;
  short* hst = dir ? hstb : hstf;
  const int w0 = dir ? w0b : w0f;

  sv8 wf[3][4];
  float bh[3];
#pragma unroll
  for (int g = 0; g < 3; ++g) {
    const short* wp = whh + (size_t)(g * HB + hc0 + l15) * HB + q * 8;
#pragma unroll
    for (int k = 0; k < 4; ++k) wf[g][k] = *(const sv8*)(wp + k * 32);
    bh[g] = bhh[g * HB + hc0 + l15];
  }

  if (tid < 256) {  // init h state (swizzled), 2048 shorts
    const int i = tid * 8, row = i >> 7, col = i & 127;
    const int sa = row * HB + (col ^ ((row & 7) << 3));
    if (first) {
      sv8 z = {0, 0, 0, 0, 0, 0, 0, 0};
      *(sv8*)&hl[0][sa] = z;
    } else {
      *(sv8*)&hl[0][sa] = *(const sv8*)(hst + (size_t)(r0 + row) * HB + col);
    }
  }
  const int f0 = tid * 8;
  const int row0 = f0 / GL, col0 = f0 % GL;
  const size_t sb0 = ((size_t)(r0 + row0) * Tc) * GL + col0;
  const int f1 = 4096 + tid * 8;
  const bool has1 = f1 < NR * GL;
  const int row1 = f1 / GL, col1 = f1 % GL;
  const size_t sb1 = ((size_t)(r0 + row1) * Tc) * GL + col1;

  {
    const int t0 = dir ? (Tc - 1) : 0;
    *(sv8*)&xgl[0][f0] = *(const sv8*)(xg + sb0 + (size_t)t0 * GL);
    if (has1) *(sv8*)&xgl[0][f1] = *(const sv8*)(xg + sb1 + (size_t)t0 * GL);
  }
  __syncthreads();

  const int swz = (l15 & 7) << 3;
  const int qs = (q * 8) ^ (swz & 24);
  const int sh = swz & 32;

  for (int t = 0; t < Tc; ++t) {
    const int cur = t & 1, nxt = cur ^ 1;
    const int tl = dir ? (Tc - 1 - t) : t;
    sv8 pf0, pf1;
    if (t + 1 < Tc) {
      const int tn = dir ? (Tc - 2 - t) : (t + 1);
      pf0 = *(const sv8*)(xg + sb0 + (size_t)tn * GL);
      if (has1) pf1 = *(const sv8*)(xg + sb1 + (size_t)tn * GL);
    }
    fv4 acc[3];
#pragma unroll
    for (int g = 0; g < 3; ++g) acc[g] = (fv4){0.f, 0.f, 0.f, 0.f};
    const short* hb = &hl[cur][l15 * HB];
#pragma unroll
    for (int k = 0; k < 4; ++k) {
      sv8 a = *(const sv8*)(hb + (((k * 32) ^ sh) + qs));
#pragma unroll
      for (int g = 0; g < 3; ++g)
        acc[g] = __builtin_amdgcn_mfma_f32_16x16x32_bf16(a, wf[g][k], acc[g], 0, 0, 0);
    }
    const int c = hc0 + l15;
#pragma unroll
    for (int j = 0; j < 4; ++j) {
      const int row = q * 4 + j;
      const short* xr = &xgl[cur][row * GL + c];
      float rr = sigm(bf2f(xr[0]) + acc[0][j] + bh[0]);
      float zz = sigm(bf2f(xr[HB]) + acc[1][j] + bh[1]);
      float nn = tanh_f(bf2f(xr[2 * HB]) + rr * (acc[2][j] + bh[2]));
      const int hidx = row * HB + (c ^ ((row & 7) << 3));
      float hp = bf2f(hl[cur][hidx]);
      float hv = (1.f - zz) * nn + zz * hp;
      short hbf = f2bf(hv);
      hl[nxt][hidx] = hbf;
      hout[((size_t)(r0 + row) * T + w0 + tl) * HO + dir * HB + c] = hbf;
    }
    if (t + 1 < Tc) {
      *(sv8*)&xgl[nxt][f0] = pf0;
      if (has1) *(sv8*)&xgl[nxt][f1] = pf1;
    }
    __syncthreads();
  }
  if (tid < 256) {  // store checkpoint
    const int i = tid * 8, row = i >> 7, col = i & 127;
    sv8 v = *(const sv8*)&hl[Tc & 1][row * HB + (col ^ ((row & 7) << 3))];
    *(sv8*)(hst + (size_t)(r0 + row) * HB + col) = v;
  }
}

// ---------------------------------------------------------------------------
// scores: sc[b*512 + w0 + tl] = dot(s1[r,:128], w2) + b2, r = b*Tc + tl
// ---------------------------------------------------------------------------
__global__ __launch_bounds__(256) void att_scores(
    const short* __restrict__ s1, const float* __restrict__ w2,
    const float* __restrict__ b2, float* __restrict__ sc, int w0, int l2tc) {
  const int r = blockIdx.x * 256 + threadIdx.x;
  const int b = r >> l2tc, tl = r & ((1 << l2tc) - 1);
  const short* p = s1 + (size_t)r * 128;
  float sum = 0.f;
#pragma unroll
  for (int c = 0; c < 16; ++c) {
    sv8 v = *(const sv8*)(p + c * 8);
#pragma unroll
    for (int j = 0; j < 8; ++j) sum += bf2f(v[j]) * w2[c * 8 + j];
  }
  sc[b * 512 + w0 + tl] = sum + b2[0];
}

// ---------------------------------------------------------------------------
// Per-batch: softmax over T, ctx = sum w_t*h_t, BN, FC 256->128->64->1.
// ---------------------------------------------------------------------------
__global__ __launch_bounds__(256) void pool_head(
    const float* __restrict__ sc, const short* __restrict__ h,
    const float* __restrict__ bng, const float* __restrict__ bnb,
    const float* __restrict__ bnm, const float* __restrict__ bnv,
    const float* __restrict__ w1, const float* __restrict__ b1,
    const float* __restrict__ w2, const float* __restrict__ b2,
    const float* __restrict__ w3, const float* __restrict__ b3,
    float* __restrict__ out) {
  constexpr int T = 512, H = 256;
  __shared__ float wts[T];
  __shared__ float red[4];
  __shared__ float ctxs[H];
  __shared__ float o1[128];
  __shared__ float o2[64];
  const int b = blockIdx.x, tid = threadIdx.x, lane = tid & 63, wv = tid >> 6;

  float s0 = sc[b * T + tid], s1v = sc[b * T + 256 + tid];
  float m = fmaxf(s0, s1v);
#pragma unroll
  for (int o = 32; o >= 1; o >>= 1) m = fmaxf(m, __shfl_xor(m, o));
  if (lane == 0) red[wv] = m;
  __syncthreads();
  m = fmaxf(fmaxf(red[0], red[1]), fmaxf(red[2], red[3]));

  float e0 = __expf(s0 - m), e1 = __expf(s1v - m);
  wts[tid] = e0; wts[tid + 256] = e1;
  float se = e0 + e1;
#pragma unroll
  for (int o = 32; o >= 1; o >>= 1) se += __shfl_xor(se, o);
  __syncthreads();                       // protect red WAR, publish wts
  if (lane == 0) red[wv] = se;
  __syncthreads();
  const float Z = red[0] + red[1] + red[2] + red[3];

  float cx = 0.f;
  const short* hp = h + (size_t)b * T * H + tid;
  for (int t = 0; t < T; ++t) cx += wts[t] * bf2f(hp[(size_t)t * H]);
  cx /= Z;
  cx = (cx - bnm[tid]) * rsqrtf(bnv[tid] + 1e-5f) * bng[tid] + bnb[tid];
  ctxs[tid] = cx;
  __syncthreads();

  if (tid < 128) {
    const float* wr = w1 + tid * H;
    float a = 0.f;
#pragma unroll 8
    for (int k = 0; k < H; ++k) a += ctxs[k] * wr[k];
    o1[tid] = fmaxf(a + b1[tid], 0.f);
  }
  __syncthreads();
  if (tid < 64) {
    const float* wr = w2 + tid * 128;
    float a = 0.f;
#pragma unroll 8
    for (int k = 0; k < 128; ++k) a += o1[k] * wr[k];
    o2[tid] = fmaxf(a + b2[tid], 0.f);
  }
  __syncthreads();
  if (tid < 64) {
    float p = o2[tid] * w3[tid];
#pragma unroll
    for (int o = 32; o >= 1; o >>= 1) p += __shfl_xor(p, o);
    if (tid == 0) out[b] = p + b3[0];
  }
}

// ---------------------------------------------------------------------------
extern "C" void kernel_launch(void* const* d_in, const int* in_sizes, int n_in,
                              void* d_out, int out_size, void* d_ws, size_t ws_size,
                              hipStream_t stream) {
  const float* x_f    = (const float*)d_in[0];
  const float* rwih0  = (const float*)d_in[1];
  const float* rwhh0  = (const float*)d_in[2];
  const float* rbih0  = (const float*)d_in[3];
  const float* rbhh0  = (const float*)d_in[4];
  const float* rwih1  = (const float*)d_in[5];
  const float* rwhh1  = (const float*)d_in[6];
  const float* rbih1  = (const float*)d_in[7];
  const float* rbhh1  = (const float*)d_in[8];
  const float* gwih_f = (const float*)d_in[9];
  const float* gwhh_f = (const float*)d_in[10];
  const float* gbih   = (const float*)d_in[11];
  const float* gbhh   = (const float*)d_in[12];
  const float* bwih_f = (const float*)d_in[13];
  const float* bwhh_f = (const float*)d_in[14];
  const float* bbih   = (const float*)d_in[15];
  const float* bbhh   = (const float*)d_in[16];
  const float* aw1_f  = (const float*)d_in[17];
  const float* ab1    = (const float*)d_in[18];
  const float* aw2    = (const float*)d_in[19];
  const float* ab2    = (const float*)d_in[20];
  const float* bng    = (const float*)d_in[21];
  const float* bnb    = (const float*)d_in[22];
  const float* bnm    = (const float*)d_in[23];
  const float* bnv    = (const float*)d_in[24];
  const float* fw1    = (const float*)d_in[25];
  const float* fb1    = (const float*)d_in[26];
  const float* fw2    = (const float*)d_in[27];
  const float* fb2    = (const float*)d_in[28];
  const float* fw3    = (const float*)d_in[29];
  const float* fb3    = (const float*)d_in[30];
  (void)in_sizes; (void)n_in; (void)out_size;

  char* ws = (char*)d_ws;
  size_t off = 0;
  auto take = [&](size_t bytes) -> char* {
    char* p = ws + off;
    off += (bytes + 255) & ~(size_t)255;
    return p;
  };
  short* wih0 = (short*)take(16384 * 2);
  short* whh0 = (short*)take(65536 * 2);
  short* wih1 = (short*)take(65536 * 2);
  short* whh1 = (short*)take(65536 * 2);
  short* gwih = (short*)take(393216 * 2);
  short* gwhh = (short*)take(393216 * 2);
  short* bwih = (short*)take(393216 * 2);
  short* bwhh = (short*)take(196608 * 2);
  short* aw1  = (short*)take(32768 * 2);
  short* hstA = (short*)take(65536 * 2);   // [256,256]
  short* hstF = (short*)take(32768 * 2);   // [256,128]
  short* hstB = (short*)take(32768 * 2);
  float* SC   = (float*)take(131072ull * 4);
  short* H1   = (short*)take(131072ull * 256 * 2);
  short* H2   = (short*)take(131072ull * 256 * 2);

  // Pick the largest T-chunk whose gate buffer fits the remaining workspace.
  const size_t region = ws_size > off ? ws_size - off : 0;
  const size_t XGF = 131072ull * 768 * 2;            // full [B,T,768] bf16
  int NC;
  if      (region >= XGF)      NC = 1;
  else if (region >= XGF / 2)  NC = 2;
  else if (region >= XGF / 4)  NC = 4;
  else if (region >= XGF / 8)  NC = 8;
  else if (region >= XGF / 16) NC = 16;
  else                         NC = 32;              // 6 MB; last resort
  const int Tc = 512 / NC;
  int l2 = 0; while ((1 << l2) < Tc) ++l2;
  short* XG  = (short*)(ws + off);                   // chunk gate buffer
  short* XGb = XG + (size_t)256 * Tc * 384;          // bi-GRU bwd half

#define CONV(src, dst, n) f2b4<<<(n) / 1024, 256, 0, stream>>>(src, dst, (n) / 4)
  CONV(rwih0, wih0, 16384);
  CONV(rwhh0, whh0, 65536);
  CONV(rwih1, wih1, 65536);
  CONV(rwhh1, whh1, 65536);
  CONV(gwih_f, gwih, 393216);
  CONV(gwhh_f, gwhh, 393216);
  CONV(bwih_f, bwih, 393216);
  CONV(bwhh_f, bwhh, 196608);
  CONV(aw1_f, aw1, 32768);
#undef CONV

  const int gg = 2 * Tc;   // gemm grid (256*Tc/128)

  // ---- rnn0 (A = fp32 x, K=64) ----
  for (int c = 0; c < NC; ++c) {
    gemm_xw<2, 0, true><<<gg, 256, 0, stream>>>(x_f, wih0, rbih0, XG, 256, 256, 0, c * Tc, l2);
    rnn_scan<<<16, 512, 0, stream>>>(XG, whh0, rbhh0, H1, c * Tc, Tc, c == 0, hstA);
  }
  // ---- rnn1 (in-place on H1) ----
  for (int c = 0; c < NC; ++c) {
    gemm_xw<8, 0, false><<<gg, 256, 0, stream>>>(H1, wih1, rbih1, XG, 256, 256, 0, c * Tc, l2);
    rnn_scan<<<16, 512, 0, stream>>>(XG, whh1, rbhh1, H1, c * Tc, Tc, c == 0, hstA);
  }
  // ---- gru0 / gru1 (in-place on H1) ----
  for (int c = 0; c < NC; ++c) {
    gemm_xw<8, 0, false><<<gg, 256, 0, stream>>>(H1, gwih, gbih, XG, 768, 768, 0, c * Tc, l2);
    gru_scan<<<16, 512, 0, stream>>>(XG, gwhh, gbhh, H1, c * Tc, Tc, c == 0, hstA);
  }
  for (int c = 0; c < NC; ++c) {
    gemm_xw<8, 0, false><<<gg, 256, 0, stream>>>(H1, gwih + 196608, gbih + 768, XG, 768, 768, 0, c * Tc, l2);
    gru_scan<<<16, 512, 0, stream>>>(XG, gwhh + 196608, gbhh + 768, H1, c * Tc, Tc, c == 0, hstA);
  }
  // ---- bi-gru layer 0: H1 -> H2 ----
  for (int s = 0; s < NC; ++s) {
    const int w0f = s * Tc, w0b = (NC - 1 - s) * Tc;
    gemm_xw<8, 0, false><<<gg, 256, 0, stream>>>(H1, bwih, bbih, XG, 384, 384, 0, w0f, l2);
    gemm_xw<8, 0, false><<<gg, 256, 0, stream>>>(H1, bwih + 98304, bbih + 384, XGb, 384, 384, 0, w0b, l2);
    bigru_scan<<<32, 512, 0, stream>>>(XG, XGb, bwhh, bwhh + 49152, bbhh, bbhh + 384,
                                       H2, w0f, w0b, Tc, s == 0, hstF, hstB);
  }
  // ---- bi-gru layer 1: H2 -> H1 ----
  for (int s = 0; s < NC; ++s) {
    const int w0f = s * Tc, w0b = (NC - 1 - s) * Tc;
    gemm_xw<8, 0, false><<<gg, 256, 0, stream>>>(H2, bwih + 2 * 98304, bbih + 768, XG, 384, 384, 0, w0f, l2);
    gemm_xw<8, 0, false><<<gg, 256, 0, stream>>>(H2, bwih + 3 * 98304, bbih + 1152, XGb, 384, 384, 0, w0b, l2);
    bigru_scan<<<32, 512, 0, stream>>>(XG, XGb, bwhh + 2 * 49152, bwhh + 3 * 49152,
                                       bbhh + 768, bbhh + 1152, H1, w0f, w0b, Tc, s == 0, hstF, hstB);
  }
  // ---- attention + head (reads H1) ----
  for (int c = 0; c < NC; ++c) {
    gemm_xw<8, 1, false><<<gg, 256, 0, stream>>>(H1, aw1, ab1, XG, 128, 128, 0, c * Tc, l2);
    att_scores<<<Tc, 256, 0, stream>>>(XG, aw2, ab2, SC, c * Tc, l2);
  }
  pool_head<<<256, 256, 0, stream>>>(SC, H1, bng, bnb, bnm, bnv,
                                     fw1, fb1, fw2, fb2, fw3, fb3, (float*)d_out);
}

// Round 3
// 5613.992 us; speedup vs baseline: 1.5288x; 1.5288x over previous
//
#include <hip/hip_runtime.h>

// ---------------------------------------------------------------------------
// AdvancedStockRNN on MI355X.  B=256 T=512 DIN=64 H=256 HB=128.
// Scans restructured (round 3): 256-thr WGs (4 waves, 1 wave/SIMD, 512-reg
// budget so recurrent weights stay register-resident), per-step phase split:
//   A: MFMA h@Whh^T -> fp32 S-buffer in LDS   (barrier)
//   B: dense re-packed epilogue: vector loads of S + xg(regs), gate math,
//      vector hl/hout writes                   (barrier)
// 8 batch rows/WG -> 32 WGs uni / 64 WGs bi.  bhh folded into GEMM bias for
// r,z,rnn gates (bias_prep); bhh_n kept in epilogue (scaled by r).
// ---------------------------------------------------------------------------

typedef short sv8 __attribute__((ext_vector_type(8)));   // 8 bf16 (4 VGPR)
typedef short sv4 __attribute__((ext_vector_type(4)));
typedef float fv4 __attribute__((ext_vector_type(4)));

__device__ __forceinline__ float bf2f(short s) {
  union { unsigned u; float f; } v; v.u = ((unsigned)(unsigned short)s) << 16; return v.f;
}
__device__ __forceinline__ short f2bf(float f) {
  union { float f; unsigned u; } v; v.f = f;
  unsigned r = (v.u + 0x7fffu + ((v.u >> 16) & 1u)) >> 16;
  return (short)r;
}
__device__ __forceinline__ float sigm(float x) { return 1.f / (1.f + __expf(-x)); }
__device__ __forceinline__ float tanh_f(float x) {
  float ax = fabsf(x);
  float e = __expf(2.f * ax);              // overflow -> inf -> t = 1
  float t = 1.f - 2.f / (e + 1.f);
  return copysignf(t, x);
}

// ---------------------------------------------------------------------------
// fp32 -> bf16 convert, 4 elems/thread (n % 1024 == 0)
// ---------------------------------------------------------------------------
__global__ __launch_bounds__(256) void f2b4(const float* __restrict__ s,
                                            short* __restrict__ d, int n4) {
  int i = blockIdx.x * 256 + threadIdx.x;
  if (i < n4) {
    fv4 v = ((const fv4*)s)[i];
    sv4 o;
    o[0] = f2bf(v[0]); o[1] = f2bf(v[1]); o[2] = f2bf(v[2]); o[3] = f2bf(v[3]);
    ((sv4*)d)[i] = o;
  }
}

// ---------------------------------------------------------------------------
// Combined biases: BC[0:256) rnn0=bih+bhh; [256:512) rnn1; [512:2048) gru
// l*768+c (c<512 += bhh); [2048:3584) bi d*384+c (c<256 += bhh).
// ---------------------------------------------------------------------------
__global__ __launch_bounds__(256) void bias_prep(
    const float* __restrict__ rbih0, const float* __restrict__ rbhh0,
    const float* __restrict__ rbih1, const float* __restrict__ rbhh1,
    const float* __restrict__ gbih, const float* __restrict__ gbhh,
    const float* __restrict__ bbih, const float* __restrict__ bbhh,
    float* __restrict__ BC) {
  int i = blockIdx.x * 256 + threadIdx.x;
  if (i >= 3584) return;
  float v;
  if (i < 256)       v = rbih0[i] + rbhh0[i];
  else if (i < 512)  { int c = i - 256; v = rbih1[c] + rbhh1[c]; }
  else if (i < 2048) { int j = i - 512; int c = j % 768;
                       v = gbih[j] + (c < 512 ? gbhh[j] : 0.f); }
  else               { int j = i - 2048; int c = j % 384;
                       v = bbih[j] + (c < 256 ? bbhh[j] : 0.f); }
  BC[i] = v;
}

// ---------------------------------------------------------------------------
// GEMM: C[r,:](bf16) = act(A[arow(r),:K] @ W[N,K]^T + bias), chunk-local C.
// r = b*Tc + tl; arow = b*512 + w0 + tl.  256 thr = 4 waves, 32 rows/wave,
// A-frags in registers, W streamed (L2-resident).  grid.x = 256*Tc/128.
// ---------------------------------------------------------------------------
template <int KS, int ACT, bool AF32>
__global__ __launch_bounds__(256, 4) void gemm_xw(
    const void* __restrict__ Av, const short* __restrict__ W,
    const float* __restrict__ bias, short* __restrict__ C,
    int N, int ldc, int w0, int l2tc) {
  const int K = KS * 32;
  const int lane = threadIdx.x & 63, wv = threadIdx.x >> 6;
  const int l15 = lane & 15, q = lane >> 4;
  const int m0 = blockIdx.x * 128 + wv * 32;
  const int tcm = (1 << l2tc) - 1;

  sv8 af[2][KS];
#pragma unroll
  for (int s = 0; s < 2; ++s) {
    const int r = m0 + s * 16 + l15;
    const size_t arow = (size_t)(r >> l2tc) * 512 + w0 + (r & tcm);
    if (AF32) {
      const float* ap = (const float*)Av + arow * K + q * 8;
#pragma unroll
      for (int k = 0; k < KS; ++k) {
        fv4 lo = *(const fv4*)(ap + k * 32);
        fv4 hi = *(const fv4*)(ap + k * 32 + 4);
        sv8 o;
        o[0] = f2bf(lo[0]); o[1] = f2bf(lo[1]); o[2] = f2bf(lo[2]); o[3] = f2bf(lo[3]);
        o[4] = f2bf(hi[0]); o[5] = f2bf(hi[1]); o[6] = f2bf(hi[2]); o[7] = f2bf(hi[3]);
        af[s][k] = o;
      }
    } else {
      const short* ap = (const short*)Av + arow * K + q * 8;
#pragma unroll
      for (int k = 0; k < KS; ++k) af[s][k] = *(const sv8*)(ap + k * 32);
    }
  }
  const int N16 = N >> 4;
  for (int nt = 0; nt < N16; ++nt) {
    const short* wp = W + (size_t)(nt * 16 + l15) * K + q * 8;
    fv4 acc0 = {0.f, 0.f, 0.f, 0.f}, acc1 = {0.f, 0.f, 0.f, 0.f};
#pragma unroll
    for (int k = 0; k < KS; ++k) {
      sv8 bf = *(const sv8*)(wp + k * 32);
      acc0 = __builtin_amdgcn_mfma_f32_16x16x32_bf16(af[0][k], bf, acc0, 0, 0, 0);
      acc1 = __builtin_amdgcn_mfma_f32_16x16x32_bf16(af[1][k], bf, acc1, 0, 0, 0);
    }
    float bv = bias[nt * 16 + l15];
#pragma unroll
    for (int s = 0; s < 2; ++s) {
      fv4 a = s ? acc1 : acc0;
#pragma unroll
      for (int j = 0; j < 4; ++j) {
        float v = a[j] + bv;
        if (ACT == 1) v = tanh_f(v);
        int row = m0 + s * 16 + q * 4 + j;
        C[(size_t)row * ldc + nt * 16 + l15] = f2bf(v);
      }
    }
  }
}

// ---------------------------------------------------------------------------
// tanh-RNN scan chunk.  grid 32 x 256thr (4 waves x 64 cols), 8 rows/WG.
// xg: [B,Tc,256] bf16 chunk (bih+bhh folded).  whh: [256,256] bf16.
// ---------------------------------------------------------------------------
__global__ __launch_bounds__(256, 1) void rnn_scan(
    const short* __restrict__ xg, const short* __restrict__ whh,
    short* __restrict__ hout, int w0, int Tc, int first,
    short* __restrict__ hst) {
  constexpr int T = 512, H = 256, NR = 8, SP = H + 8;
  __shared__ __align__(16) short hl[NR * H];
  __shared__ __align__(16) float S[NR * SP];
  const int tid = threadIdx.x, lane = tid & 63, wv = tid >> 6;
  const int l15 = lane & 15, q = lane >> 4;
  const int r0 = blockIdx.x * NR;

  sv8 wf[4][8];
#pragma unroll
  for (int s = 0; s < 4; ++s) {
    const short* wp = whh + (size_t)(wv * 64 + s * 16 + l15) * H + q * 8;
#pragma unroll
    for (int k = 0; k < 8; ++k) wf[s][k] = *(const sv8*)(wp + k * 32);
  }
  const int brow = tid >> 5, bcb = tid & 31;
  const int hlo = brow * H + ((bcb * 8) ^ (brow << 3));
  const size_t xbase = ((size_t)(r0 + brow) * Tc) * H + bcb * 8;
  const size_t obase = ((size_t)(r0 + brow) * T + w0) * H + bcb * 8;

  sv8 hvv;
  if (first) { sv8 z = {0,0,0,0,0,0,0,0}; hvv = z; }
  else hvv = *(const sv8*)(hst + (size_t)(r0 + brow) * H + bcb * 8);
  *(sv8*)&hl[hlo] = hvv;
  sv8 xr = *(const sv8*)(xg + xbase);
  __syncthreads();

  const int arow = l15 & 7;
  const short* hb = hl + arow * H;
  const int asw = arow << 3;

  for (int t = 0; t < Tc; ++t) {
    fv4 acc[4] = {{0,0,0,0},{0,0,0,0},{0,0,0,0},{0,0,0,0}};
#pragma unroll
    for (int k = 0; k < 8; ++k) {
      sv8 a = *(const sv8*)(hb + ((k * 32 + q * 8) ^ asw));
#pragma unroll
      for (int s = 0; s < 4; ++s)
        acc[s] = __builtin_amdgcn_mfma_f32_16x16x32_bf16(a, wf[s][k], acc[s], 0, 0, 0);
    }
    if (q < 2) {
#pragma unroll
      for (int s = 0; s < 4; ++s)
#pragma unroll
        for (int j = 0; j < 4; ++j)
          S[(q * 4 + j) * SP + wv * 64 + s * 16 + l15] = acc[s][j];
    }
    __syncthreads();
    const float* sp = &S[brow * SP + bcb * 8];
    fv4 slo = *(const fv4*)sp, shi = *(const fv4*)(sp + 4);
    sv8 o;
#pragma unroll
    for (int i = 0; i < 4; ++i) o[i] = f2bf(tanh_f(bf2f(xr[i]) + slo[i]));
#pragma unroll
    for (int i = 0; i < 4; ++i) o[4 + i] = f2bf(tanh_f(bf2f(xr[4 + i]) + shi[i]));
    hvv = o;
    *(sv8*)&hl[hlo] = o;
    *(sv8*)(hout + obase + (size_t)t * H) = o;
    if (t + 1 < Tc) xr = *(const sv8*)(xg + xbase + (size_t)(t + 1) * H);
    __syncthreads();
  }
  *(sv8*)(hst + (size_t)(r0 + brow) * H + bcb * 8) = hvv;
}

// ---------------------------------------------------------------------------
// GRU scan chunk.  grid 32 x 256thr (4 waves x 192 gate-cols), 8 rows/WG.
// xg: [B,Tc,768] bf16 (bih + bhh_{r,z} folded).  whh: [768,256] bf16.
// bhn: bhh_n (256 floats).
// ---------------------------------------------------------------------------
__global__ __launch_bounds__(256, 1) void gru_scan(
    const short* __restrict__ xg, const short* __restrict__ whh,
    const float* __restrict__ bhn, short* __restrict__ hout,
    int w0, int Tc, int first, short* __restrict__ hst) {
  constexpr int T = 512, H = 256, G = 768, NR = 8, SP = H + 8;
  __shared__ __align__(16) short hl[NR * H];
  __shared__ __align__(16) float S[3 * NR * SP];
  const int tid = threadIdx.x, lane = tid & 63, wv = tid >> 6;
  const int l15 = lane & 15, q = lane >> 4;
  const int r0 = blockIdx.x * NR;

  sv8 wf[3][4][8];
#pragma unroll
  for (int g = 0; g < 3; ++g)
#pragma unroll
    for (int s = 0; s < 4; ++s) {
      const short* wp = whh + (size_t)(g * H + wv * 64 + s * 16 + l15) * H + q * 8;
#pragma unroll
      for (int k = 0; k < 8; ++k) wf[g][s][k] = *(const sv8*)(wp + k * 32);
    }
  const int brow = tid >> 5, bcb = tid & 31;
  const int hlo = brow * H + ((bcb * 8) ^ (brow << 3));
  const size_t xbase = ((size_t)(r0 + brow) * Tc) * G + bcb * 8;
  const size_t obase = ((size_t)(r0 + brow) * T + w0) * H + bcb * 8;
  const float* bp = bhn + bcb * 8;
  fv4 bn0 = *(const fv4*)bp, bn1 = *(const fv4*)(bp + 4);

  sv8 hp;
  if (first) { sv8 z = {0,0,0,0,0,0,0,0}; hp = z; }
  else hp = *(const sv8*)(hst + (size_t)(r0 + brow) * H + bcb * 8);
  *(sv8*)&hl[hlo] = hp;
  sv8 xr0 = *(const sv8*)(xg + xbase);
  sv8 xr1 = *(const sv8*)(xg + xbase + 256);
  sv8 xr2 = *(const sv8*)(xg + xbase + 512);
  __syncthreads();

  const int arow = l15 & 7;
  const short* hb = hl + arow * H;
  const int asw = arow << 3;

  for (int t = 0; t < Tc; ++t) {
    fv4 acc[3][4];
#pragma unroll
    for (int g = 0; g < 3; ++g)
#pragma unroll
      for (int s = 0; s < 4; ++s) acc[g][s] = (fv4){0,0,0,0};
#pragma unroll
    for (int k = 0; k < 8; ++k) {
      sv8 a = *(const sv8*)(hb + ((k * 32 + q * 8) ^ asw));
#pragma unroll
      for (int g = 0; g < 3; ++g)
#pragma unroll
        for (int s = 0; s < 4; ++s)
          acc[g][s] = __builtin_amdgcn_mfma_f32_16x16x32_bf16(a, wf[g][s][k], acc[g][s], 0, 0, 0);
    }
    if (q < 2) {
#pragma unroll
      for (int g = 0; g < 3; ++g)
#pragma unroll
        for (int s = 0; s < 4; ++s)
#pragma unroll
          for (int j = 0; j < 4; ++j)
            S[(g * NR + q * 4 + j) * SP + wv * 64 + s * 16 + l15] = acc[g][s][j];
    }
    __syncthreads();
    const float* s0 = &S[(0 * NR + brow) * SP + bcb * 8];
    const float* s1 = &S[(1 * NR + brow) * SP + bcb * 8];
    const float* s2 = &S[(2 * NR + brow) * SP + bcb * 8];
    fv4 r0v = *(const fv4*)s0, r1v = *(const fv4*)(s0 + 4);
    fv4 z0v = *(const fv4*)s1, z1v = *(const fv4*)(s1 + 4);
    fv4 n0v = *(const fv4*)s2, n1v = *(const fv4*)(s2 + 4);
    sv8 o;
#pragma unroll
    for (int i = 0; i < 4; ++i) {
      float rr = sigm(bf2f(xr0[i]) + r0v[i]);
      float zz = sigm(bf2f(xr1[i]) + z0v[i]);
      float nn = tanh_f(bf2f(xr2[i]) + rr * (n0v[i] + bn0[i]));
      o[i] = f2bf((1.f - zz) * nn + zz * bf2f(hp[i]));
    }
#pragma unroll
    for (int i = 0; i < 4; ++i) {
      float rr = sigm(bf2f(xr0[4 + i]) + r1v[i]);
      float zz = sigm(bf2f(xr1[4 + i]) + z1v[i]);
      float nn = tanh_f(bf2f(xr2[4 + i]) + rr * (n1v[i] + bn1[i]));
      o[4 + i] = f2bf((1.f - zz) * nn + zz * bf2f(hp[4 + i]));
    }
    hp = o;
    *(sv8*)&hl[hlo] = o;
    *(sv8*)(hout + obase + (size_t)t * H) = o;
    if (t + 1 < Tc) {
      const size_t xb = xbase + (size_t)(t + 1) * G;
      xr0 = *(const sv8*)(xg + xb);
      xr1 = *(const sv8*)(xg + xb + 256);
      xr2 = *(const sv8*)(xg + xb + 512);
    }
    __syncthreads();
  }
  *(sv8*)(hst + (size_t)(r0 + brow) * H + bcb * 8) = hp;
}

// ---------------------------------------------------------------------------
// bi-GRU scan chunk.  grid 64 x 256thr: dir = bid>>5, 8 rows/WG.
// xgf/xgb: [B,Tc,384] bf16 (bih + bhh_{r,z} folded).  whh: [384,128] bf16.
// hout: [B,T,256] (fwd cols 0..127, bwd 128..255).  bhn: bhh_n (128 floats).
// ---------------------------------------------------------------------------
__global__ __launch_bounds__(256, 1) void bigru_scan(
    const short* __restrict__ xgf, const short* __restrict__ xgb,
    const short* __restrict__ whh_f, const short* __restrict__ whh_b,
    const float* __restrict__ bhn_f, const float* __restrict__ bhn_b,
    short* __restrict__ hout, int w0f, int w0b, int Tc, int first,
    short* __restrict__ hstf, short* __restrict__ hstb) {
  constexpr int T = 512, HB = 128, GL = 384, NR = 8, SP = HB + 8, HO = 256;
  __shared__ __align__(16) short hl[NR * HB];
  __shared__ __align__(16) float S[3 * NR * SP];
  const int tid = threadIdx.x, lane = tid & 63, wv = tid >> 6;
  const int l15 = lane & 15, q = lane >> 4;
  const int dir = blockIdx.x >> 5;
  const int r0 = (blockIdx.x & 31) * NR;
  const short* whh = dir ? whh_b : whh_f;
  const short* xg  = dir ? xgb : xgf;
  const float* bhn = dir ? bhn_b : bhn_f;
  short* hst = dir ? hstb : hstf;
  const int w0 = dir ? w0b : w0f;

  sv8 wf[3][2][4];
#pragma unroll
  for (int g = 0; g < 3; ++g)
#pragma unroll
    for (int s = 0; s < 2; ++s) {
      const short* wp = whh + (size_t)(g * HB + wv * 32 + s * 16 + l15) * HB + q * 8;
#pragma unroll
      for (int k = 0; k < 4; ++k) wf[g][s][k] = *(const sv8*)(wp + k * 32);
    }
  const int brow = tid >> 5, bcb = tid & 31;
  const int hlo = brow * HB + ((bcb * 4) ^ (brow << 3));
  const size_t xbase = ((size_t)(r0 + brow) * Tc) * GL + bcb * 4;
  const size_t obase = ((size_t)(r0 + brow) * T + w0) * HO + dir * HB + bcb * 4;
  fv4 bn = *(const fv4*)(bhn + bcb * 4);

  sv4 hp;
  if (first) { sv4 z = {0,0,0,0}; hp = z; }
  else hp = *(const sv4*)(hst + (size_t)(r0 + brow) * HB + bcb * 4);
  *(sv4*)&hl[hlo] = hp;
  int tl = dir ? (Tc - 1) : 0;
  sv4 xr0 = *(const sv4*)(xg + xbase + (size_t)tl * GL);
  sv4 xr1 = *(const sv4*)(xg + xbase + (size_t)tl * GL + 128);
  sv4 xr2 = *(const sv4*)(xg + xbase + (size_t)tl * GL + 256);
  __syncthreads();

  const int arow = l15 & 7;
  const short* hb = hl + arow * HB;
  const int asw = arow << 3;

  for (int t = 0; t < Tc; ++t) {
    tl = dir ? (Tc - 1 - t) : t;
    fv4 acc[3][2];
#pragma unroll
    for (int g = 0; g < 3; ++g)
#pragma unroll
      for (int s = 0; s < 2; ++s) acc[g][s] = (fv4){0,0,0,0};
#pragma unroll
    for (int k = 0; k < 4; ++k) {
      sv8 a = *(const sv8*)(hb + ((k * 32 + q * 8) ^ asw));
#pragma unroll
      for (int g = 0; g < 3; ++g)
#pragma unroll
        for (int s = 0; s < 2; ++s)
          acc[g][s] = __builtin_amdgcn_mfma_f32_16x16x32_bf16(a, wf[g][s][k], acc[g][s], 0, 0, 0);
    }
    if (q < 2) {
#pragma unroll
      for (int g = 0; g < 3; ++g)
#pragma unroll
        for (int s = 0; s < 2; ++s)
#pragma unroll
          for (int j = 0; j < 4; ++j)
            S[(g * NR + q * 4 + j) * SP + wv * 32 + s * 16 + l15] = acc[g][s][j];
    }
    __syncthreads();
    fv4 sr = *(const fv4*)&S[(0 * NR + brow) * SP + bcb * 4];
    fv4 sz = *(const fv4*)&S[(1 * NR + brow) * SP + bcb * 4];
    fv4 sn = *(const fv4*)&S[(2 * NR + brow) * SP + bcb * 4];
    sv4 o;
#pragma unroll
    for (int i = 0; i < 4; ++i) {
      float rr = sigm(bf2f(xr0[i]) + sr[i]);
      float zz = sigm(bf2f(xr1[i]) + sz[i]);
      float nn = tanh_f(bf2f(xr2[i]) + rr * (sn[i] + bn[i]));
      o[i] = f2bf((1.f - zz) * nn + zz * bf2f(hp[i]));
    }
    hp = o;
    *(sv4*)&hl[hlo] = o;
    *(sv4*)(hout + obase + (size_t)tl * HO) = o;
    if (t + 1 < Tc) {
      const int tn = dir ? (Tc - 2 - t) : (t + 1);
      const size_t xb = xbase + (size_t)tn * GL;
      xr0 = *(const sv4*)(xg + xb);
      xr1 = *(const sv4*)(xg + xb + 128);
      xr2 = *(const sv4*)(xg + xb + 256);
    }
    __syncthreads();
  }
  *(sv4*)(hst + (size_t)(r0 + brow) * HB + bcb * 4) = hp;
}

// ---------------------------------------------------------------------------
// scores: sc[b*512 + w0 + tl] = dot(s1[r,:128], w2) + b2, r = b*Tc + tl
// ---------------------------------------------------------------------------
__global__ __launch_bounds__(256) void att_scores(
    const short* __restrict__ s1, const float* __restrict__ w2,
    const float* __restrict__ b2, float* __restrict__ sc, int w0, int l2tc) {
  const int r = blockIdx.x * 256 + threadIdx.x;
  const int b = r >> l2tc, tl = r & ((1 << l2tc) - 1);
  const short* p = s1 + (size_t)r * 128;
  float sum = 0.f;
#pragma unroll
  for (int c = 0; c < 16; ++c) {
    sv8 v = *(const sv8*)(p + c * 8);
#pragma unroll
    for (int j = 0; j < 8; ++j) sum += bf2f(v[j]) * w2[c * 8 + j];
  }
  sc[b * 512 + w0 + tl] = sum + b2[0];
}

// ---------------------------------------------------------------------------
// Per-batch: softmax over T, ctx = sum w_t*h_t, BN, FC 256->128->64->1.
// ---------------------------------------------------------------------------
__global__ __launch_bounds__(256) void pool_head(
    const float* __restrict__ sc, const short* __restrict__ h,
    const float* __restrict__ bng, const float* __restrict__ bnb,
    const float* __restrict__ bnm, const float* __restrict__ bnv,
    const float* __restrict__ w1, const float* __restrict__ b1,
    const float* __restrict__ w2, const float* __restrict__ b2,
    const float* __restrict__ w3, const float* __restrict__ b3,
    float* __restrict__ out) {
  constexpr int T = 512, H = 256;
  __shared__ float wts[T];
  __shared__ float red[4];
  __shared__ float ctxs[H];
  __shared__ float o1[128];
  __shared__ float o2[64];
  const int b = blockIdx.x, tid = threadIdx.x, lane = tid & 63, wv = tid >> 6;

  float s0 = sc[b * T + tid], s1v = sc[b * T + 256 + tid];
  float m = fmaxf(s0, s1v);
#pragma unroll
  for (int o = 32; o >= 1; o >>= 1) m = fmaxf(m, __shfl_xor(m, o));
  if (lane == 0) red[wv] = m;
  __syncthreads();
  m = fmaxf(fmaxf(red[0], red[1]), fmaxf(red[2], red[3]));

  float e0 = __expf(s0 - m), e1 = __expf(s1v - m);
  wts[tid] = e0; wts[tid + 256] = e1;
  float se = e0 + e1;
#pragma unroll
  for (int o = 32; o >= 1; o >>= 1) se += __shfl_xor(se, o);
  __syncthreads();
  if (lane == 0) red[wv] = se;
  __syncthreads();
  const float Z = red[0] + red[1] + red[2] + red[3];

  float cx = 0.f;
  const short* hp = h + (size_t)b * T * H + tid;
  for (int t = 0; t < T; ++t) cx += wts[t] * bf2f(hp[(size_t)t * H]);
  cx /= Z;
  cx = (cx - bnm[tid]) * rsqrtf(bnv[tid] + 1e-5f) * bng[tid] + bnb[tid];
  ctxs[tid] = cx;
  __syncthreads();

  if (tid < 128) {
    const float* wr = w1 + tid * H;
    float a = 0.f;
#pragma unroll 8
    for (int k = 0; k < H; ++k) a += ctxs[k] * wr[k];
    o1[tid] = fmaxf(a + b1[tid], 0.f);
  }
  __syncthreads();
  if (tid < 64) {
    const float* wr = w2 + tid * 128;
    float a = 0.f;
#pragma unroll 8
    for (int k = 0; k < 128; ++k) a += o1[k] * wr[k];
    o2[tid] = fmaxf(a + b2[tid], 0.f);
  }
  __syncthreads();
  if (tid < 64) {
    float p = o2[tid] * w3[tid];
#pragma unroll
    for (int o = 32; o >= 1; o >>= 1) p += __shfl_xor(p, o);
    if (tid == 0) out[b] = p + b3[0];
  }
}

// ---------------------------------------------------------------------------
extern "C" void kernel_launch(void* const* d_in, const int* in_sizes, int n_in,
                              void* d_out, int out_size, void* d_ws, size_t ws_size,
                              hipStream_t stream) {
  const float* x_f    = (const float*)d_in[0];
  const float* rwih0  = (const float*)d_in[1];
  const float* rwhh0  = (const float*)d_in[2];
  const float* rbih0  = (const float*)d_in[3];
  const float* rbhh0  = (const float*)d_in[4];
  const float* rwih1  = (const float*)d_in[5];
  const float* rwhh1  = (const float*)d_in[6];
  const float* rbih1  = (const float*)d_in[7];
  const float* rbhh1  = (const float*)d_in[8];
  const float* gwih_f = (const float*)d_in[9];
  const float* gwhh_f = (const float*)d_in[10];
  const float* gbih   = (const float*)d_in[11];
  const float* gbhh   = (const float*)d_in[12];
  const float* bwih_f = (const float*)d_in[13];
  const float* bwhh_f = (const float*)d_in[14];
  const float* bbih   = (const float*)d_in[15];
  const float* bbhh   = (const float*)d_in[16];
  const float* aw1_f  = (const float*)d_in[17];
  const float* ab1    = (const float*)d_in[18];
  const float* aw2    = (const float*)d_in[19];
  const float* ab2    = (const float*)d_in[20];
  const float* bng    = (const float*)d_in[21];
  const float* bnb    = (const float*)d_in[22];
  const float* bnm    = (const float*)d_in[23];
  const float* bnv    = (const float*)d_in[24];
  const float* fw1    = (const float*)d_in[25];
  const float* fb1    = (const float*)d_in[26];
  const float* fw2    = (const float*)d_in[27];
  const float* fb2    = (const float*)d_in[28];
  const float* fw3    = (const float*)d_in[29];
  const float* fb3    = (const float*)d_in[30];
  (void)in_sizes; (void)n_in; (void)out_size;

  char* ws = (char*)d_ws;
  size_t off = 0;
  auto take = [&](size_t bytes) -> char* {
    char* p = ws + off;
    off += (bytes + 255) & ~(size_t)255;
    return p;
  };
  short* wih0 = (short*)take(16384 * 2);
  short* whh0 = (short*)take(65536 * 2);
  short* wih1 = (short*)take(65536 * 2);
  short* whh1 = (short*)take(65536 * 2);
  short* gwih = (short*)take(393216 * 2);
  short* gwhh = (short*)take(393216 * 2);
  short* bwih = (short*)take(393216 * 2);
  short* bwhh = (short*)take(196608 * 2);
  short* aw1  = (short*)take(32768 * 2);
  float* BC   = (float*)take(3584 * 4);
  short* hstA = (short*)take(65536 * 2);   // [256,256]
  short* hstF = (short*)take(32768 * 2);   // [256,128]
  short* hstB = (short*)take(32768 * 2);
  float* SC   = (float*)take(131072ull * 4);
  short* H1   = (short*)take(131072ull * 256 * 2);
  short* H2   = (short*)take(131072ull * 256 * 2);

  const size_t region = ws_size > off ? ws_size - off : 0;
  const size_t XGF = 131072ull * 768 * 2;            // full [B,T,768] bf16
  int NC;
  if      (region >= XGF)      NC = 1;
  else if (region >= XGF / 2)  NC = 2;
  else if (region >= XGF / 4)  NC = 4;
  else if (region >= XGF / 8)  NC = 8;
  else if (region >= XGF / 16) NC = 16;
  else                         NC = 32;
  const int Tc = 512 / NC;
  int l2 = 0; while ((1 << l2) < Tc) ++l2;
  short* XG  = (short*)(ws + off);
  short* XGb = XG + (size_t)256 * Tc * 384;

#define CONV(src, dst, n) f2b4<<<(n) / 1024, 256, 0, stream>>>(src, dst, (n) / 4)
  CONV(rwih0, wih0, 16384);
  CONV(rwhh0, whh0, 65536);
  CONV(rwih1, wih1, 65536);
  CONV(rwhh1, whh1, 65536);
  CONV(gwih_f, gwih, 393216);
  CONV(gwhh_f, gwhh, 393216);
  CONV(bwih_f, bwih, 393216);
  CONV(bwhh_f, bwhh, 196608);
  CONV(aw1_f, aw1, 32768);
#undef CONV
  bias_prep<<<14, 256, 0, stream>>>(rbih0, rbhh0, rbih1, rbhh1,
                                    gbih, gbhh, bbih, bbhh, BC);

  const int gg = 2 * Tc;

  // ---- rnn0 (A = fp32 x, K=64) ----
  for (int c = 0; c < NC; ++c) {
    gemm_xw<2, 0, true><<<gg, 256, 0, stream>>>(x_f, wih0, BC, XG, 256, 256, c * Tc, l2);
    rnn_scan<<<32, 256, 0, stream>>>(XG, whh0, H1, c * Tc, Tc, c == 0, hstA);
  }
  // ---- rnn1 ----
  for (int c = 0; c < NC; ++c) {
    gemm_xw<8, 0, false><<<gg, 256, 0, stream>>>(H1, wih1, BC + 256, XG, 256, 256, c * Tc, l2);
    rnn_scan<<<32, 256, 0, stream>>>(XG, whh1, H1, c * Tc, Tc, c == 0, hstA);
  }
  // ---- gru0 / gru1 ----
  for (int c = 0; c < NC; ++c) {
    gemm_xw<8, 0, false><<<gg, 256, 0, stream>>>(H1, gwih, BC + 512, XG, 768, 768, c * Tc, l2);
    gru_scan<<<32, 256, 0, stream>>>(XG, gwhh, gbhh + 512, H1, c * Tc, Tc, c == 0, hstA);
  }
  for (int c = 0; c < NC; ++c) {
    gemm_xw<8, 0, false><<<gg, 256, 0, stream>>>(H1, gwih + 196608, BC + 1280, XG, 768, 768, c * Tc, l2);
    gru_scan<<<32, 256, 0, stream>>>(XG, gwhh + 196608, gbhh + 768 + 512, H1, c * Tc, Tc, c == 0, hstA);
  }
  // ---- bi-gru layer 0: H1 -> H2 ----
  for (int s = 0; s < NC; ++s) {
    const int w0f = s * Tc, w0b = (NC - 1 - s) * Tc;
    gemm_xw<8, 0, false><<<gg, 256, 0, stream>>>(H1, bwih, BC + 2048, XG, 384, 384, w0f, l2);
    gemm_xw<8, 0, false><<<gg, 256, 0, stream>>>(H1, bwih + 98304, BC + 2432, XGb, 384, 384, w0b, l2);
    bigru_scan<<<64, 256, 0, stream>>>(XG, XGb, bwhh, bwhh + 49152,
                                       bbhh + 256, bbhh + 384 + 256,
                                       H2, w0f, w0b, Tc, s == 0, hstF, hstB);
  }
  // ---- bi-gru layer 1: H2 -> H1 ----
  for (int s = 0; s < NC; ++s) {
    const int w0f = s * Tc, w0b = (NC - 1 - s) * Tc;
    gemm_xw<8, 0, false><<<gg, 256, 0, stream>>>(H2, bwih + 2 * 98304, BC + 2816, XG, 384, 384, w0f, l2);
    gemm_xw<8, 0, false><<<gg, 256, 0, stream>>>(H2, bwih + 3 * 98304, BC + 3200, XGb, 384, 384, w0b, l2);
    bigru_scan<<<64, 256, 0, stream>>>(XG, XGb, bwhh + 2 * 49152, bwhh + 3 * 49152,
                                       bbhh + 2 * 384 + 256, bbhh + 3 * 384 + 256,
                                       H1, w0f, w0b, Tc, s == 0, hstF, hstB);
  }
  // ---- attention + head (reads H1) ----
  for (int c = 0; c < NC; ++c) {
    gemm_xw<8, 1, false><<<gg, 256, 0, stream>>>(H1, aw1, ab1, XG, 128, 128, c * Tc, l2);
    att_scores<<<Tc, 256, 0, stream>>>(XG, aw2, ab2, SC, c * Tc, l2);
  }
  pool_head<<<256, 256, 0, stream>>>(SC, H1, bng, bnb, bnm, bnv,
                                     fw1, fb1, fw2, fb2, fw3, fb3, (float*)d_out);
}

// Round 4
// 5502.614 us; speedup vs baseline: 1.5598x; 1.0202x over previous
//
#include <hip/hip_runtime.h>

// ---------------------------------------------------------------------------
// AdvancedStockRNN on MI355X.  B=256 T=512 DIN=64 H=256 HB=128.
// Round 4: scan WGs are 512 thr (8 waves, 2 waves/SIMD, 256-VGPR budget) so
// recurrent weights (<=192 VGPR/wave) stay in arch VGPRs (no AGPR moves).
// Per step: phase A (MFMA h@Whh^T -> fp32 S in LDS), barrier, phase B
// (one batch-row per wave, 4 (2) hidden cols per thread: vector S-reads,
// gate math, vector h writes), barrier.
// ---------------------------------------------------------------------------

typedef short sv8 __attribute__((ext_vector_type(8)));   // 8 bf16 (4 VGPR)
typedef short sv4 __attribute__((ext_vector_type(4)));
typedef short sv2 __attribute__((ext_vector_type(2)));
typedef float fv4 __attribute__((ext_vector_type(4)));
typedef float fv2 __attribute__((ext_vector_type(2)));

__device__ __forceinline__ float bf2f(short s) {
  union { unsigned u; float f; } v; v.u = ((unsigned)(unsigned short)s) << 16; return v.f;
}
__device__ __forceinline__ short f2bf(float f) {
  union { float f; unsigned u; } v; v.f = f;
  unsigned r = (v.u + 0x7fffu + ((v.u >> 16) & 1u)) >> 16;
  return (short)r;
}
__device__ __forceinline__ float sigm(float x) { return 1.f / (1.f + __expf(-x)); }
__device__ __forceinline__ float tanh_f(float x) {
  float ax = fabsf(x);
  float e = __expf(2.f * ax);              // overflow -> inf -> t = 1
  float t = 1.f - 2.f / (e + 1.f);
  return copysignf(t, x);
}

// ---------------------------------------------------------------------------
// fp32 -> bf16 convert, 4 elems/thread (n % 1024 == 0)
// ---------------------------------------------------------------------------
__global__ __launch_bounds__(256) void f2b4(const float* __restrict__ s,
                                            short* __restrict__ d, int n4) {
  int i = blockIdx.x * 256 + threadIdx.x;
  if (i < n4) {
    fv4 v = ((const fv4*)s)[i];
    sv4 o;
    o[0] = f2bf(v[0]); o[1] = f2bf(v[1]); o[2] = f2bf(v[2]); o[3] = f2bf(v[3]);
    ((sv4*)d)[i] = o;
  }
}

// ---------------------------------------------------------------------------
// Combined biases: BC[0:256) rnn0=bih+bhh; [256:512) rnn1; [512:2048) gru
// l*768+c (c<512 += bhh); [2048:3584) bi d*384+c (c<256 += bhh).
// ---------------------------------------------------------------------------
__global__ __launch_bounds__(256) void bias_prep(
    const float* __restrict__ rbih0, const float* __restrict__ rbhh0,
    const float* __restrict__ rbih1, const float* __restrict__ rbhh1,
    const float* __restrict__ gbih, const float* __restrict__ gbhh,
    const float* __restrict__ bbih, const float* __restrict__ bbhh,
    float* __restrict__ BC) {
  int i = blockIdx.x * 256 + threadIdx.x;
  if (i >= 3584) return;
  float v;
  if (i < 256)       v = rbih0[i] + rbhh0[i];
  else if (i < 512)  { int c = i - 256; v = rbih1[c] + rbhh1[c]; }
  else if (i < 2048) { int j = i - 512; int c = j % 768;
                       v = gbih[j] + (c < 512 ? gbhh[j] : 0.f); }
  else               { int j = i - 2048; int c = j % 384;
                       v = bbih[j] + (c < 256 ? bbhh[j] : 0.f); }
  BC[i] = v;
}

// ---------------------------------------------------------------------------
// GEMM: C[r,:](bf16) = act(A[arow(r),:K] @ W[N,K]^T + bias), chunk-local C.
// r = b*Tc + tl; arow = b*512 + w0 + tl.  256 thr = 4 waves, 32 rows/wave,
// A-frags in registers, W streamed (L2-resident).  grid.x = 256*Tc/128.
// ---------------------------------------------------------------------------
template <int KS, int ACT, bool AF32>
__global__ __launch_bounds__(256, 4) void gemm_xw(
    const void* __restrict__ Av, const short* __restrict__ W,
    const float* __restrict__ bias, short* __restrict__ C,
    int N, int ldc, int w0, int l2tc) {
  const int K = KS * 32;
  const int lane = threadIdx.x & 63, wv = threadIdx.x >> 6;
  const int l15 = lane & 15, q = lane >> 4;
  const int m0 = blockIdx.x * 128 + wv * 32;
  const int tcm = (1 << l2tc) - 1;

  sv8 af[2][KS];
#pragma unroll
  for (int s = 0; s < 2; ++s) {
    const int r = m0 + s * 16 + l15;
    const size_t arow = (size_t)(r >> l2tc) * 512 + w0 + (r & tcm);
    if (AF32) {
      const float* ap = (const float*)Av + arow * K + q * 8;
#pragma unroll
      for (int k = 0; k < KS; ++k) {
        fv4 lo = *(const fv4*)(ap + k * 32);
        fv4 hi = *(const fv4*)(ap + k * 32 + 4);
        sv8 o;
        o[0] = f2bf(lo[0]); o[1] = f2bf(lo[1]); o[2] = f2bf(lo[2]); o[3] = f2bf(lo[3]);
        o[4] = f2bf(hi[0]); o[5] = f2bf(hi[1]); o[6] = f2bf(hi[2]); o[7] = f2bf(hi[3]);
        af[s][k] = o;
      }
    } else {
      const short* ap = (const short*)Av + arow * K + q * 8;
#pragma unroll
      for (int k = 0; k < KS; ++k) af[s][k] = *(const sv8*)(ap + k * 32);
    }
  }
  const int N16 = N >> 4;
  for (int nt = 0; nt < N16; ++nt) {
    const short* wp = W + (size_t)(nt * 16 + l15) * K + q * 8;
    fv4 acc0 = {0.f, 0.f, 0.f, 0.f}, acc1 = {0.f, 0.f, 0.f, 0.f};
#pragma unroll
    for (int k = 0; k < KS; ++k) {
      sv8 bf = *(const sv8*)(wp + k * 32);
      acc0 = __builtin_amdgcn_mfma_f32_16x16x32_bf16(af[0][k], bf, acc0, 0, 0, 0);
      acc1 = __builtin_amdgcn_mfma_f32_16x16x32_bf16(af[1][k], bf, acc1, 0, 0, 0);
    }
    float bv = bias[nt * 16 + l15];
#pragma unroll
    for (int s = 0; s < 2; ++s) {
      fv4 a = s ? acc1 : acc0;
#pragma unroll
      for (int j = 0; j < 4; ++j) {
        float v = a[j] + bv;
        if (ACT == 1) v = tanh_f(v);
        int row = m0 + s * 16 + q * 4 + j;
        C[(size_t)row * ldc + nt * 16 + l15] = f2bf(v);
      }
    }
  }
}

// ---------------------------------------------------------------------------
// tanh-RNN scan chunk.  grid 32 x 512thr (8 waves x 32 cols), 8 rows/WG.
// xg: [B,Tc,256] bf16 chunk (bih+bhh folded).  whh: [256,256] bf16.
// ---------------------------------------------------------------------------
__global__ __launch_bounds__(512, 2) void rnn_scan(
    const short* __restrict__ xg, const short* __restrict__ whh,
    short* __restrict__ hout, int w0, int Tc, int first,
    short* __restrict__ hst) {
  constexpr int T = 512, H = 256, NR = 8, SP = H + 8;
  __shared__ __align__(16) short hl[NR * H];
  __shared__ __align__(16) float S[NR * SP];
  const int tid = threadIdx.x, lane = tid & 63, wv = tid >> 6;
  const int l15 = lane & 15, q = lane >> 4;
  const int r0 = blockIdx.x * NR;

  sv8 wf[2][8];
#pragma unroll
  for (int s = 0; s < 2; ++s) {
    const short* wp = whh + (size_t)(wv * 32 + s * 16 + l15) * H + q * 8;
#pragma unroll
    for (int k = 0; k < 8; ++k) wf[s][k] = *(const sv8*)(wp + k * 32);
  }
  const int row = wv;            // epilogue row (one per wave)
  const int c = (tid & 63) * 4;  // epilogue cols (4 per thread)
  const size_t xbase = ((size_t)(r0 + row) * Tc) * H + c;
  const size_t obase = ((size_t)(r0 + row) * T + w0) * H + c;
  const int hlo = row * H + (c ^ (row << 3));

  sv4 hp;
  if (first) { sv4 z = {0,0,0,0}; hp = z; }
  else hp = *(const sv4*)(hst + (size_t)(r0 + row) * H + c);
  *(sv4*)&hl[hlo] = hp;
  sv4 xr = *(const sv4*)(xg + xbase);
  __syncthreads();

  const int arow = l15 & 7;
  const short* hb = hl + arow * H;
  const int asw = arow << 3;

  for (int t = 0; t < Tc; ++t) {
    fv4 acc[2] = {{0,0,0,0},{0,0,0,0}};
#pragma unroll
    for (int k = 0; k < 8; ++k) {
      sv8 a = *(const sv8*)(hb + ((k * 32 + q * 8) ^ asw));
#pragma unroll
      for (int s = 0; s < 2; ++s)
        acc[s] = __builtin_amdgcn_mfma_f32_16x16x32_bf16(a, wf[s][k], acc[s], 0, 0, 0);
    }
    if (q < 2) {
#pragma unroll
      for (int s = 0; s < 2; ++s)
#pragma unroll
        for (int j = 0; j < 4; ++j)
          S[(q * 4 + j) * SP + wv * 32 + s * 16 + l15] = acc[s][j];
    }
    __syncthreads();
    fv4 sv = *(const fv4*)&S[row * SP + c];
    sv4 o;
#pragma unroll
    for (int i = 0; i < 4; ++i) o[i] = f2bf(tanh_f(bf2f(xr[i]) + sv[i]));
    hp = o;
    *(sv4*)&hl[hlo] = o;
    *(sv4*)(hout + obase + (size_t)t * H) = o;
    if (t + 1 < Tc) xr = *(const sv4*)(xg + xbase + (size_t)(t + 1) * H);
    __syncthreads();
  }
  *(sv4*)(hst + (size_t)(r0 + row) * H + c) = hp;
}

// ---------------------------------------------------------------------------
// GRU scan chunk.  grid 32 x 512thr (8 waves x 96 gate-cols), 8 rows/WG.
// xg: [B,Tc,768] bf16 (bih + bhh_{r,z} folded).  whh: [768,256] bf16.
// bhn: bhh_n (256 floats).
// ---------------------------------------------------------------------------
__global__ __launch_bounds__(512, 2) void gru_scan(
    const short* __restrict__ xg, const short* __restrict__ whh,
    const float* __restrict__ bhn, short* __restrict__ hout,
    int w0, int Tc, int first, short* __restrict__ hst) {
  constexpr int T = 512, H = 256, G = 768, NR = 8, SP = G + 8;
  __shared__ __align__(16) short hl[NR * H];
  __shared__ __align__(16) float S[NR * SP];
  const int tid = threadIdx.x, lane = tid & 63, wv = tid >> 6;
  const int l15 = lane & 15, q = lane >> 4;
  const int r0 = blockIdx.x * NR;

  sv8 wf[6][8];
#pragma unroll
  for (int s = 0; s < 6; ++s) {
    const short* wp = whh + (size_t)(wv * 96 + s * 16 + l15) * H + q * 8;
#pragma unroll
    for (int k = 0; k < 8; ++k) wf[s][k] = *(const sv8*)(wp + k * 32);
  }
  const int row = wv;
  const int c = (tid & 63) * 4;
  const size_t xbase = ((size_t)(r0 + row) * Tc) * G + c;
  const size_t obase = ((size_t)(r0 + row) * T + w0) * H + c;
  const int hlo = row * H + (c ^ (row << 3));
  fv4 bn = *(const fv4*)(bhn + c);

  sv4 hp;
  if (first) { sv4 z = {0,0,0,0}; hp = z; }
  else hp = *(const sv4*)(hst + (size_t)(r0 + row) * H + c);
  *(sv4*)&hl[hlo] = hp;
  sv4 xr0 = *(const sv4*)(xg + xbase);
  sv4 xr1 = *(const sv4*)(xg + xbase + 256);
  sv4 xr2 = *(const sv4*)(xg + xbase + 512);
  __syncthreads();

  const int arow = l15 & 7;
  const short* hb = hl + arow * H;
  const int asw = arow << 3;

  for (int t = 0; t < Tc; ++t) {
    fv4 acc[6];
#pragma unroll
    for (int s = 0; s < 6; ++s) acc[s] = (fv4){0,0,0,0};
#pragma unroll
    for (int k = 0; k < 8; ++k) {
      sv8 a = *(const sv8*)(hb + ((k * 32 + q * 8) ^ asw));
#pragma unroll
      for (int s = 0; s < 6; ++s)
        acc[s] = __builtin_amdgcn_mfma_f32_16x16x32_bf16(a, wf[s][k], acc[s], 0, 0, 0);
    }
    if (q < 2) {
#pragma unroll
      for (int s = 0; s < 6; ++s)
#pragma unroll
        for (int j = 0; j < 4; ++j)
          S[(q * 4 + j) * SP + wv * 96 + s * 16 + l15] = acc[s][j];
    }
    __syncthreads();
    fv4 sr = *(const fv4*)&S[row * SP + c];
    fv4 sz = *(const fv4*)&S[row * SP + c + 256];
    fv4 sn = *(const fv4*)&S[row * SP + c + 512];
    sv4 o;
#pragma unroll
    for (int i = 0; i < 4; ++i) {
      float rr = sigm(bf2f(xr0[i]) + sr[i]);
      float zz = sigm(bf2f(xr1[i]) + sz[i]);
      float nn = tanh_f(bf2f(xr2[i]) + rr * (sn[i] + bn[i]));
      o[i] = f2bf((1.f - zz) * nn + zz * bf2f(hp[i]));
    }
    hp = o;
    *(sv4*)&hl[hlo] = o;
    *(sv4*)(hout + obase + (size_t)t * H) = o;
    if (t + 1 < Tc) {
      const size_t xb = xbase + (size_t)(t + 1) * G;
      xr0 = *(const sv4*)(xg + xb);
      xr1 = *(const sv4*)(xg + xb + 256);
      xr2 = *(const sv4*)(xg + xb + 512);
    }
    __syncthreads();
  }
  *(sv4*)(hst + (size_t)(r0 + row) * H + c) = hp;
}

// ---------------------------------------------------------------------------
// bi-GRU scan chunk.  grid 64 x 512thr (8 waves x 48 gate-cols), 8 rows/WG.
// dir = bid>>5.  xgf/xgb: [B,Tc,384] bf16 (bih + bhh_{r,z} folded).
// whh: [384,128] bf16.  hout: [B,T,256] (fwd 0..127, bwd 128..255).
// ---------------------------------------------------------------------------
__global__ __launch_bounds__(512, 2) void bigru_scan(
    const short* __restrict__ xgf, const short* __restrict__ xgb,
    const short* __restrict__ whh_f, const short* __restrict__ whh_b,
    const float* __restrict__ bhn_f, const float* __restrict__ bhn_b,
    short* __restrict__ hout, int w0f, int w0b, int Tc, int first,
    short* __restrict__ hstf, short* __restrict__ hstb) {
  constexpr int T = 512, HB = 128, GL = 384, NR = 8, SP = GL + 8, HO = 256;
  __shared__ __align__(16) short hl[NR * HB];
  __shared__ __align__(16) float S[NR * SP];
  const int tid = threadIdx.x, lane = tid & 63, wv = tid >> 6;
  const int l15 = lane & 15, q = lane >> 4;
  const int dir = blockIdx.x >> 5;
  const int r0 = (blockIdx.x & 31) * NR;
  const short* whh = dir ? whh_b : whh_f;
  const short* xg  = dir ? xgb : xgf;
  const float* bhn = dir ? bhn_b : bhn_f;
  short* hst = dir ? hstb : hstf;
  const int w0 = dir ? w0b : w0f;

  sv8 wf[3][4];
#pragma unroll
  for (int s = 0; s < 3; ++s) {
    const short* wp = whh + (size_t)(wv * 48 + s * 16 + l15) * HB + q * 8;
#pragma unroll
    for (int k = 0; k < 4; ++k) wf[s][k] = *(const sv8*)(wp + k * 32);
  }
  const int row = wv;
  const int c = (tid & 63) * 2;
  const size_t xbase = ((size_t)(r0 + row) * Tc) * GL + c;
  const size_t obase = ((size_t)(r0 + row) * T + w0) * HO + dir * HB + c;
  const int hlo = row * HB + (c ^ (row << 3));
  fv2 bn = *(const fv2*)(bhn + c);

  sv2 hp;
  if (first) { sv2 z = {0,0}; hp = z; }
  else hp = *(const sv2*)(hst + (size_t)(r0 + row) * HB + c);
  *(sv2*)&hl[hlo] = hp;
  int tl = dir ? (Tc - 1) : 0;
  sv2 xr0 = *(const sv2*)(xg + xbase + (size_t)tl * GL);
  sv2 xr1 = *(const sv2*)(xg + xbase + (size_t)tl * GL + 128);
  sv2 xr2 = *(const sv2*)(xg + xbase + (size_t)tl * GL + 256);
  __syncthreads();

  const int arow = l15 & 7;
  const short* hb = hl + arow * HB;
  const int asw = arow << 3;

  for (int t = 0; t < Tc; ++t) {
    tl = dir ? (Tc - 1 - t) : t;
    fv4 acc[3];
#pragma unroll
    for (int s = 0; s < 3; ++s) acc[s] = (fv4){0,0,0,0};
#pragma unroll
    for (int k = 0; k < 4; ++k) {
      sv8 a = *(const sv8*)(hb + ((k * 32 + q * 8) ^ asw));
#pragma unroll
      for (int s = 0; s < 3; ++s)
        acc[s] = __builtin_amdgcn_mfma_f32_16x16x32_bf16(a, wf[s][k], acc[s], 0, 0, 0);
    }
    if (q < 2) {
#pragma unroll
      for (int s = 0; s < 3; ++s)
#pragma unroll
        for (int j = 0; j < 4; ++j)
          S[(q * 4 + j) * SP + wv * 48 + s * 16 + l15] = acc[s][j];
    }
    __syncthreads();
    fv2 sr = *(const fv2*)&S[row * SP + c];
    fv2 sz = *(const fv2*)&S[row * SP + c + 128];
    fv2 sn = *(const fv2*)&S[row * SP + c + 256];
    sv2 o;
#pragma unroll
    for (int i = 0; i < 2; ++i) {
      float rr = sigm(bf2f(xr0[i]) + sr[i]);
      float zz = sigm(bf2f(xr1[i]) + sz[i]);
      float nn = tanh_f(bf2f(xr2[i]) + rr * (sn[i] + bn[i]));
      o[i] = f2bf((1.f - zz) * nn + zz * bf2f(hp[i]));
    }
    hp = o;
    *(sv2*)&hl[hlo] = o;
    *(sv2*)(hout + obase + (size_t)tl * HO) = o;
    if (t + 1 < Tc) {
      const int tn = dir ? (Tc - 2 - t) : (t + 1);
      const size_t xb = xbase + (size_t)tn * GL;
      xr0 = *(const sv2*)(xg + xb);
      xr1 = *(const sv2*)(xg + xb + 128);
      xr2 = *(const sv2*)(xg + xb + 256);
    }
    __syncthreads();
  }
  *(sv2*)(hst + (size_t)(r0 + row) * HB + c) = hp;
}

// ---------------------------------------------------------------------------
// scores: sc[b*512 + w0 + tl] = dot(s1[r,:128], w2) + b2, r = b*Tc + tl
// ---------------------------------------------------------------------------
__global__ __launch_bounds__(256) void att_scores(
    const short* __restrict__ s1, const float* __restrict__ w2,
    const float* __restrict__ b2, float* __restrict__ sc, int w0, int l2tc) {
  const int r = blockIdx.x * 256 + threadIdx.x;
  const int b = r >> l2tc, tl = r & ((1 << l2tc) - 1);
  const short* p = s1 + (size_t)r * 128;
  float sum = 0.f;
#pragma unroll
  for (int c = 0; c < 16; ++c) {
    sv8 v = *(const sv8*)(p + c * 8);
#pragma unroll
    for (int j = 0; j < 8; ++j) sum += bf2f(v[j]) * w2[c * 8 + j];
  }
  sc[b * 512 + w0 + tl] = sum + b2[0];
}

// ---------------------------------------------------------------------------
// Per-batch: softmax over T, ctx = sum w_t*h_t, BN, FC 256->128->64->1.
// ---------------------------------------------------------------------------
__global__ __launch_bounds__(256) void pool_head(
    const float* __restrict__ sc, const short* __restrict__ h,
    const float* __restrict__ bng, const float* __restrict__ bnb,
    const float* __restrict__ bnm, const float* __restrict__ bnv,
    const float* __restrict__ w1, const float* __restrict__ b1,
    const float* __restrict__ w2, const float* __restrict__ b2,
    const float* __restrict__ w3, const float* __restrict__ b3,
    float* __restrict__ out) {
  constexpr int T = 512, H = 256;
  __shared__ float wts[T];
  __shared__ float red[4];
  __shared__ float ctxs[H];
  __shared__ float o1[128];
  __shared__ float o2[64];
  const int b = blockIdx.x, tid = threadIdx.x, lane = tid & 63, wv = tid >> 6;

  float s0 = sc[b * T + tid], s1v = sc[b * T + 256 + tid];
  float m = fmaxf(s0, s1v);
#pragma unroll
  for (int o = 32; o >= 1; o >>= 1) m = fmaxf(m, __shfl_xor(m, o));
  if (lane == 0) red[wv] = m;
  __syncthreads();
  m = fmaxf(fmaxf(red[0], red[1]), fmaxf(red[2], red[3]));

  float e0 = __expf(s0 - m), e1 = __expf(s1v - m);
  wts[tid] = e0; wts[tid + 256] = e1;
  float se = e0 + e1;
#pragma unroll
  for (int o = 32; o >= 1; o >>= 1) se += __shfl_xor(se, o);
  __syncthreads();
  if (lane == 0) red[wv] = se;
  __syncthreads();
  const float Z = red[0] + red[1] + red[2] + red[3];

  float cx = 0.f;
  const short* hp = h + (size_t)b * T * H + tid;
  for (int t = 0; t < T; ++t) cx += wts[t] * bf2f(hp[(size_t)t * H]);
  cx /= Z;
  cx = (cx - bnm[tid]) * rsqrtf(bnv[tid] + 1e-5f) * bng[tid] + bnb[tid];
  ctxs[tid] = cx;
  __syncthreads();

  if (tid < 128) {
    const float* wr = w1 + tid * H;
    float a = 0.f;
#pragma unroll 8
    for (int k = 0; k < H; ++k) a += ctxs[k] * wr[k];
    o1[tid] = fmaxf(a + b1[tid], 0.f);
  }
  __syncthreads();
  if (tid < 64) {
    const float* wr = w2 + tid * 128;
    float a = 0.f;
#pragma unroll 8
    for (int k = 0; k < 128; ++k) a += o1[k] * wr[k];
    o2[tid] = fmaxf(a + b2[tid], 0.f);
  }
  __syncthreads();
  if (tid < 64) {
    float p = o2[tid] * w3[tid];
#pragma unroll
    for (int o = 32; o >= 1; o >>= 1) p += __shfl_xor(p, o);
    if (tid == 0) out[b] = p + b3[0];
  }
}

// ---------------------------------------------------------------------------
extern "C" void kernel_launch(void* const* d_in, const int* in_sizes, int n_in,
                              void* d_out, int out_size, void* d_ws, size_t ws_size,
                              hipStream_t stream) {
  const float* x_f    = (const float*)d_in[0];
  const float* rwih0  = (const float*)d_in[1];
  const float* rwhh0  = (const float*)d_in[2];
  const float* rbih0  = (const float*)d_in[3];
  const float* rbhh0  = (const float*)d_in[4];
  const float* rwih1  = (const float*)d_in[5];
  const float* rwhh1  = (const float*)d_in[6];
  const float* rbih1  = (const float*)d_in[7];
  const float* rbhh1  = (const float*)d_in[8];
  const float* gwih_f = (const float*)d_in[9];
  const float* gwhh_f = (const float*)d_in[10];
  const float* gbih   = (const float*)d_in[11];
  const float* gbhh   = (const float*)d_in[12];
  const float* bwih_f = (const float*)d_in[13];
  const float* bwhh_f = (const float*)d_in[14];
  const float* bbih   = (const float*)d_in[15];
  const float* bbhh   = (const float*)d_in[16];
  const float* aw1_f  = (const float*)d_in[17];
  const float* ab1    = (const float*)d_in[18];
  const float* aw2    = (const float*)d_in[19];
  const float* ab2    = (const float*)d_in[20];
  const float* bng    = (const float*)d_in[21];
  const float* bnb    = (const float*)d_in[22];
  const float* bnm    = (const float*)d_in[23];
  const float* bnv    = (const float*)d_in[24];
  const float* fw1    = (const float*)d_in[25];
  const float* fb1    = (const float*)d_in[26];
  const float* fw2    = (const float*)d_in[27];
  const float* fb2    = (const float*)d_in[28];
  const float* fw3    = (const float*)d_in[29];
  const float* fb3    = (const float*)d_in[30];
  (void)in_sizes; (void)n_in; (void)out_size;

  char* ws = (char*)d_ws;
  size_t off = 0;
  auto take = [&](size_t bytes) -> char* {
    char* p = ws + off;
    off += (bytes + 255) & ~(size_t)255;
    return p;
  };
  short* wih0 = (short*)take(16384 * 2);
  short* whh0 = (short*)take(65536 * 2);
  short* wih1 = (short*)take(65536 * 2);
  short* whh1 = (short*)take(65536 * 2);
  short* gwih = (short*)take(393216 * 2);
  short* gwhh = (short*)take(393216 * 2);
  short* bwih = (short*)take(393216 * 2);
  short* bwhh = (short*)take(196608 * 2);
  short* aw1  = (short*)take(32768 * 2);
  float* BC   = (float*)take(3584 * 4);
  short* hstA = (short*)take(65536 * 2);   // [256,256]
  short* hstF = (short*)take(32768 * 2);   // [256,128]
  short* hstB = (short*)take(32768 * 2);
  float* SC   = (float*)take(131072ull * 4);
  short* H1   = (short*)take(131072ull * 256 * 2);
  short* H2   = (short*)take(131072ull * 256 * 2);

  const size_t region = ws_size > off ? ws_size - off : 0;
  const size_t XGF = 131072ull * 768 * 2;            // full [B,T,768] bf16
  int NC;
  if      (region >= XGF)      NC = 1;
  else if (region >= XGF / 2)  NC = 2;
  else if (region >= XGF / 4)  NC = 4;
  else if (region >= XGF / 8)  NC = 8;
  else if (region >= XGF / 16) NC = 16;
  else                         NC = 32;
  const int Tc = 512 / NC;
  int l2 = 0; while ((1 << l2) < Tc) ++l2;
  short* XG  = (short*)(ws + off);
  short* XGb = XG + (size_t)256 * Tc * 384;

#define CONV(src, dst, n) f2b4<<<(n) / 1024, 256, 0, stream>>>(src, dst, (n) / 4)
  CONV(rwih0, wih0, 16384);
  CONV(rwhh0, whh0, 65536);
  CONV(rwih1, wih1, 65536);
  CONV(rwhh1, whh1, 65536);
  CONV(gwih_f, gwih, 393216);
  CONV(gwhh_f, gwhh, 393216);
  CONV(bwih_f, bwih, 393216);
  CONV(bwhh_f, bwhh, 196608);
  CONV(aw1_f, aw1, 32768);
#undef CONV
  bias_prep<<<14, 256, 0, stream>>>(rbih0, rbhh0, rbih1, rbhh1,
                                    gbih, gbhh, bbih, bbhh, BC);

  const int gg = 2 * Tc;

  // ---- rnn0 (A = fp32 x, K=64) ----
  for (int c = 0; c < NC; ++c) {
    gemm_xw<2, 0, true><<<gg, 256, 0, stream>>>(x_f, wih0, BC, XG, 256, 256, c * Tc, l2);
    rnn_scan<<<32, 512, 0, stream>>>(XG, whh0, H1, c * Tc, Tc, c == 0, hstA);
  }
  // ---- rnn1 ----
  for (int c = 0; c < NC; ++c) {
    gemm_xw<8, 0, false><<<gg, 256, 0, stream>>>(H1, wih1, BC + 256, XG, 256, 256, c * Tc, l2);
    rnn_scan<<<32, 512, 0, stream>>>(XG, whh1, H1, c * Tc, Tc, c == 0, hstA);
  }
  // ---- gru0 / gru1 ----
  for (int c = 0; c < NC; ++c) {
    gemm_xw<8, 0, false><<<gg, 256, 0, stream>>>(H1, gwih, BC + 512, XG, 768, 768, c * Tc, l2);
    gru_scan<<<32, 512, 0, stream>>>(XG, gwhh, gbhh + 512, H1, c * Tc, Tc, c == 0, hstA);
  }
  for (int c = 0; c < NC; ++c) {
    gemm_xw<8, 0, false><<<gg, 256, 0, stream>>>(H1, gwih + 196608, BC + 1280, XG, 768, 768, c * Tc, l2);
    gru_scan<<<32, 512, 0, stream>>>(XG, gwhh + 196608, gbhh + 768 + 512, H1, c * Tc, Tc, c == 0, hstA);
  }
  // ---- bi-gru layer 0: H1 -> H2 ----
  for (int s = 0; s < NC; ++s) {
    const int w0f = s * Tc, w0b = (NC - 1 - s) * Tc;
    gemm_xw<8, 0, false><<<gg, 256, 0, stream>>>(H1, bwih, BC + 2048, XG, 384, 384, w0f, l2);
    gemm_xw<8, 0, false><<<gg, 256, 0, stream>>>(H1, bwih + 98304, BC + 2432, XGb, 384, 384, w0b, l2);
    bigru_scan<<<64, 512, 0, stream>>>(XG, XGb, bwhh, bwhh + 49152,
                                       bbhh + 256, bbhh + 384 + 256,
                                       H2, w0f, w0b, Tc, s == 0, hstF, hstB);
  }
  // ---- bi-gru layer 1: H2 -> H1 ----
  for (int s = 0; s < NC; ++s) {
    const int w0f = s * Tc, w0b = (NC - 1 - s) * Tc;
    gemm_xw<8, 0, false><<<gg, 256, 0, stream>>>(H2, bwih + 2 * 98304, BC + 2816, XG, 384, 384, w0f, l2);
    gemm_xw<8, 0, false><<<gg, 256, 0, stream>>>(H2, bwih + 3 * 98304, BC + 3200, XGb, 384, 384, w0b, l2);
    bigru_scan<<<64, 512, 0, stream>>>(XG, XGb, bwhh + 2 * 49152, bwhh + 3 * 49152,
                                       bbhh + 2 * 384 + 256, bbhh + 3 * 384 + 256,
                                       H1, w0f, w0b, Tc, s == 0, hstF, hstB);
  }
  // ---- attention + head (reads H1) ----
  for (int c = 0; c < NC; ++c) {
    gemm_xw<8, 1, false><<<gg, 256, 0, stream>>>(H1, aw1, ab1, XG, 128, 128, c * Tc, l2);
    att_scores<<<Tc, 256, 0, stream>>>(XG, aw2, ab2, SC, c * Tc, l2);
  }
  pool_head<<<256, 256, 0, stream>>>(SC, H1, bng, bnb, bnm, bnv,
                                     fw1, fb1, fw2, fb2, fw3, fb3, (float*)d_out);
}